// Round 5
// baseline (475.087 us; speedup 1.0000x reference)
//
#include <hip/hip_runtime.h>
#include <cmath>

constexpr int cB = 4, cN = 256, cD = 240, cH = 8, cFF = 1024, cL = 4;
constexpr int cHD = 30, cS = 1030, cPAST = 515, cBS = cB * cS; // 4120
constexpr int cKp = 256;   // padded K for D-sized contractions
constexpr int cSP = 1088;  // padded sequence for attention buffers
constexpr float EPSF = 1e-5f;

typedef __bf16 bf16x8 __attribute__((ext_vector_type(8)));
typedef float f32x4 __attribute__((ext_vector_type(4)));

__device__ inline unsigned short f2bf(float f) {
    unsigned int u = __builtin_bit_cast(unsigned int, f);
    unsigned int r = (u + 0x7fffu + ((u >> 16) & 1u)) >> 16;
    return (unsigned short)r;
}

// =============== setup: weight convert + zero-init + embed + coords, one dispatch ==========
constexpr int R1 = 4 * cL * 65536;          // wqkv convert
constexpr int R2 = R1 + cL * 1024 * 256;    // w1p
constexpr int R3 = R2 + cL * 256 * 1024;    // w2p
constexpr int R4 = R3 + cBS * cD;           // embed
constexpr int R5 = R4 + cBS;                // coords
constexpr size_t qkvN = (size_t)cB * cH * cSP * 32;
constexpr int nSpan32 = (int)(3 * qkvN / 2);
constexpr int R6 = R5 + nSpan32;            // q/k/vT zero span (u32)
constexpr int R7 = R6 + cBS * 8;            // pad cols of 3 activation bufs (u32 each)

__global__ __launch_bounds__(256) void setup_all(
    const float* __restrict__ Wq, const float* __restrict__ Wk,
    const float* __restrict__ Wv, const float* __restrict__ Wo,
    const float* __restrict__ W1, const float* __restrict__ W2,
    const float* __restrict__ hand_t, const float* __restrict__ head_t,
    const float* __restrict__ hand_m1, const float* __restrict__ head_m1,
    const float* __restrict__ state_t, const float* __restrict__ state_m1,
    const float* __restrict__ hand_pose_m1, const float* __restrict__ head_pose_m1,
    const float* __restrict__ hand_pose_t, const float* __restrict__ head_pose_t,
    const float* __restrict__ ch_t, const float* __restrict__ cd_t,
    const float* __restrict__ ch_m1, const float* __restrict__ cd_m1,
    unsigned short* __restrict__ wqkv, unsigned short* __restrict__ w1p,
    unsigned short* __restrict__ w2p,
    float* __restrict__ src, unsigned short* __restrict__ sbf, float* __restrict__ cs,
    unsigned int* __restrict__ qkvspan,
    unsigned short* __restrict__ padA, unsigned short* __restrict__ padB,
    unsigned short* __restrict__ padC)
{
    int idx = blockIdx.x * 256 + threadIdx.x;
    if (idx < R1) {
        int which = idx >> 18;
        const float* W = (which == 0) ? Wq : (which == 1) ? Wk : (which == 2) ? Wv : Wo;
        int rem = idx & 262143;
        int m = rem >> 16;
        int rc = rem & 65535;
        int r = rc >> 8, c = rc & 255;
        float v = (r < 240 && c < 240) ? W[((size_t)m * 240 + r) * 240 + c] : 0.f;
        wqkv[idx] = f2bf(v);
    } else if (idx < R2) {
        int rem = idx - R1;
        int m = rem >> 18;
        int rc = rem & 262143;
        int r = rc >> 8, c = rc & 255;
        float v = (c < 240) ? W1[((size_t)m * 1024 + r) * 240 + c] : 0.f;
        w1p[rem] = f2bf(v);
    } else if (idx < R3) {
        int rem = idx - R2;
        int m = rem >> 18;
        int rc = rem & 262143;
        int r = rc >> 10, c = rc & 1023;
        float v = (r < 240) ? W2[((size_t)m * 240 + r) * 1024 + c] : 0.f;
        w2p[rem] = f2bf(v);
    } else if (idx < R4) {
        int rem = idx - R3;
        int d = rem % cD;
        int r = rem / cD;
        int b = r / cS, s = r % cS;
        const float* p; int off;
        if (s == 0)                  { p = state_m1;     off = b * cD + d; }
        else if (s == 1)             { p = hand_pose_m1; off = b * cD + d; }
        else if (s == 2)             { p = head_pose_m1; off = b * cD + d; }
        else if (s < 3 + cN)         { p = hand_m1;      off = (b * cN + (s - 3)) * cD + d; }
        else if (s < 3 + 2 * cN)     { p = head_m1;      off = (b * cN + (s - 3 - cN)) * cD + d; }
        else if (s == cPAST)         { p = state_t;      off = b * cD + d; }
        else if (s == cPAST + 1)     { p = hand_pose_t;  off = b * cD + d; }
        else if (s == cPAST + 2)     { p = head_pose_t;  off = b * cD + d; }
        else if (s < cPAST + 3 + cN) { p = hand_t;       off = (b * cN + (s - cPAST - 3)) * cD + d; }
        else                         { p = head_t;       off = (b * cN + (s - cPAST - 3 - cN)) * cD + d; }
        float v = p[off];
        src[rem] = v;
        sbf[(size_t)r * cKp + d] = f2bf(v);
    } else if (idx < R5) {
        int r = idx - R4;
        int b = r / cS, s = r % cS;
        float x = 0.f, y = 0.f, z = 0.f;
        const float* p = nullptr; int i = 0;
        if (s >= 3 && s < 3 + cN)                       { p = ch_m1; i = s - 3; }
        else if (s >= 3 + cN && s < 3 + 2 * cN)         { p = cd_m1; i = s - 3 - cN; }
        else if (s >= cPAST + 3 && s < cPAST + 3 + cN)  { p = ch_t;  i = s - cPAST - 3; }
        else if (s >= cPAST + 3 + cN)                   { p = cd_t;  i = s - cPAST - 3 - cN; }
        if (p) { x = p[(b * cN + i) * 3 + 0]; y = p[(b * cN + i) * 3 + 1]; z = p[(b * cN + i) * 3 + 2]; }
        cs[r * 3 + 0] = x; cs[r * 3 + 1] = y; cs[r * 3 + 2] = z;
    } else if (idx < R6) {
        qkvspan[idx - R5] = 0u;
    } else if (idx < R7) {
        int rem = idx - R6;
        int r = rem >> 3, j = rem & 7;
        ((unsigned int*)(padA + (size_t)r * 256 + 240))[j] = 0u;
        ((unsigned int*)(padB + (size_t)r * 256 + 240))[j] = 0u;
        ((unsigned int*)(padC + (size_t)r * 256 + 240))[j] = 0u;
    }
}

// ================= MFMA GEMM core (validated round 2) =================
#define GEMM_CORE(A_PTR, W_PTR, M_, KA_, NK_)                                                 \
    __shared__ unsigned short Al[128][40];                                                    \
    __shared__ unsigned short Bl[64][40];                                                     \
    const int tid = threadIdx.x;                                                              \
    const int lane = tid & 63;                                                                \
    const int w = tid >> 6;                                                                   \
    const int wm = w >> 1, wn = w & 1;                                                        \
    const int lrow = lane & 15, kq = lane >> 4;                                               \
    const int rowBase = blockIdx.y * 128;                                                     \
    const int colBase = blockIdx.x * 64;                                                      \
    const int sRow = tid >> 2;                                                                \
    const int sS = tid & 3;                                                                   \
    const int ar0 = min(rowBase + sRow, M_ - 1);                                              \
    const int ar1 = min(rowBase + sRow + 64, M_ - 1);                                         \
    const int wr = colBase + sRow;                                                            \
    const unsigned short* a0p = A_PTR + (size_t)ar0 * KA_ + sS * 8;                           \
    const unsigned short* a1p = A_PTR + (size_t)ar1 * KA_ + sS * 8;                           \
    const unsigned short* wp  = W_PTR + (size_t)wr * KA_ + sS * 8;                            \
    f32x4 acc[4][2] = {};                                                                     \
    int4 ra0 = *(const int4*)a0p;                                                             \
    int4 ra1 = *(const int4*)a1p;                                                             \
    int4 rb  = *(const int4*)wp;                                                              \
    for (int ks = 0; ks < NK_; ++ks) {                                                        \
        __syncthreads();                                                                      \
        *(int4*)&Al[sRow][sS * 8]      = ra0;                                                 \
        *(int4*)&Al[sRow + 64][sS * 8] = ra1;                                                 \
        *(int4*)&Bl[sRow][sS * 8]      = rb;                                                  \
        __syncthreads();                                                                      \
        if (ks + 1 < NK_) {                                                                   \
            int kk = (ks + 1) * 32;                                                           \
            ra0 = *(const int4*)(a0p + kk);                                                   \
            ra1 = *(const int4*)(a1p + kk);                                                   \
            rb  = *(const int4*)(wp + kk);                                                    \
        }                                                                                     \
        bf16x8 af[4], bfr[2];                                                                 \
        _Pragma("unroll")                                                                     \
        for (int i = 0; i < 4; ++i)                                                           \
            af[i] = *(const bf16x8*)&Al[wm * 64 + i * 16 + lrow][kq * 8];                     \
        _Pragma("unroll")                                                                     \
        for (int j = 0; j < 2; ++j)                                                           \
            bfr[j] = *(const bf16x8*)&Bl[wn * 32 + j * 16 + lrow][kq * 8];                    \
        _Pragma("unroll")                                                                     \
        for (int i = 0; i < 4; ++i)                                                           \
            _Pragma("unroll")                                                                 \
            for (int j = 0; j < 2; ++j)                                                       \
                acc[i][j] = __builtin_amdgcn_mfma_f32_16x16x32_bf16(af[i], bfr[j], acc[i][j], 0, 0, 0); \
    }

// ---------------- FF1 GEMM: gelu(+bias) -> bf16 out (ld 1024) ----------------
__global__ __launch_bounds__(256) void gemm_ff1(
    const unsigned short* __restrict__ A, const unsigned short* __restrict__ W,
    const float* __restrict__ bias, unsigned short* __restrict__ outB)
{
    GEMM_CORE(A, W, cBS, cKp, 8)
#pragma unroll
    for (int i = 0; i < 4; ++i) {
#pragma unroll
        for (int j = 0; j < 2; ++j) {
            int col = colBase + wn * 32 + j * 16 + lrow;
            float bcol = bias[col];
            f32x4 v = acc[i][j];
#pragma unroll
            for (int r = 0; r < 4; ++r) {
                int row = rowBase + wm * 64 + i * 16 + kq * 4 + r;
                if (row >= cBS) continue;
                float t = v[r] + bcol;
                float gl = 0.5f * t * (1.0f + erff(t * 0.70710678118654752f));
                outB[(size_t)row * 1024 + col] = f2bf(gl);
            }
        }
    }
}

// ---------------- QKV GEMM with fused RoPE; writes bf16 q,k (BH,SP,32) and V^T (BH,32,SP) ----
__global__ __launch_bounds__(256) void gemm_qkv_rope(
    const unsigned short* __restrict__ A,
    const unsigned short* __restrict__ Wqp, const unsigned short* __restrict__ Wkp,
    const unsigned short* __restrict__ Wvp,
    const float* __restrict__ bq, const float* __restrict__ bk, const float* __restrict__ bv,
    const float* __restrict__ cs,
    unsigned short* __restrict__ qbf, unsigned short* __restrict__ kbf,
    unsigned short* __restrict__ vtbf)
{
    const int z = blockIdx.z;
    const unsigned short* Wsel = (z == 0) ? Wqp : (z == 1) ? Wkp : Wvp;
    const float* bias = (z == 0) ? bq : (z == 1) ? bk : bv;
    GEMM_CORE(A, Wsel, cBS, cKp, 8)
    if (z == 2) {
#pragma unroll
        for (int i = 0; i < 4; ++i) {
#pragma unroll
            for (int j = 0; j < 2; ++j) {
                int col = colBase + wn * 32 + j * 16 + lrow;
                if (col >= cD) continue;
                float bcol = bias[col];
                int hh = col / cHD, hd = col % cHD;
                f32x4 vv = acc[i][j];
                int row0 = rowBase + wm * 64 + i * 16 + kq * 4;
                int b0 = row0 / cS, s0 = row0 - b0 * cS;
                if (row0 + 3 < cBS && s0 + 3 < cS) {
                    unsigned int lo = (unsigned)f2bf(vv[0] + bcol) | ((unsigned)f2bf(vv[1] + bcol) << 16);
                    unsigned int hi = (unsigned)f2bf(vv[2] + bcol) | ((unsigned)f2bf(vv[3] + bcol) << 16);
                    size_t base = ((size_t)(b0 * cH + hh) * 32 + hd) * cSP + s0;
                    *(unsigned int*)&vtbf[base]     = lo;
                    *(unsigned int*)&vtbf[base + 2] = hi;
                } else {
#pragma unroll
                    for (int r = 0; r < 4; ++r) {
                        int row = row0 + r;
                        if (row >= cBS) continue;
                        int bb = row / cS, ss = row - bb * cS;
                        vtbf[((size_t)(bb * cH + hh) * 32 + hd) * cSP + ss] = f2bf(vv[r] + bcol);
                    }
                }
            }
        }
    } else {
#pragma unroll
        for (int i = 0; i < 4; ++i) {
#pragma unroll
            for (int j = 0; j < 2; ++j) {
                int col = colBase + wn * 32 + j * 16 + lrow;
                bool colok = col < cD;
                int cc = colok ? col : 0;
                float bcol = colok ? bias[cc] : 0.f;
                int hh = cc / cHD, hd = cc % cHD;
                int a3 = hd / 10, jj = (hd % 10) >> 1;
                float invf = __expf(-1.8420680743952367f * (float)jj);
                f32x4 vv = acc[i][j];
#pragma unroll
                for (int r = 0; r < 4; ++r) {
                    int row = rowBase + wm * 64 + i * 16 + kq * 4 + r;
                    bool rowok = row < cBS;
                    int rowc = rowok ? row : 0;
                    float val = vv[r] + bcol;
                    float pval = __shfl_xor(val, 1);   // partner col (pairs are adjacent lanes)
                    int b = rowc / cS, s = rowc - b * cS;
                    size_t bh = (size_t)(b * cH + hh);
                    float ang = cs[rowc * 3 + a3] * invf;
                    float sn, co;
                    __sincosf(ang, &sn, &co);
                    float outv = (hd & 1) ? (pval * sn + val * co) : (val * co - pval * sn);
                    if (colok && rowok) {
                        unsigned short* dst = (z == 0) ? qbf : kbf;
                        dst[(bh * cSP + s) * 32 + hd] = f2bf(outv);
                    }
                }
            }
        }
    }
}

// ------- MFMA flash attention, kv-split x4: 16 q-rows/block, 4 waves = 4 kv quarters -------
__global__ __launch_bounds__(256) void attn_mfma(
    const unsigned short* __restrict__ qbf, const unsigned short* __restrict__ kbf,
    const unsigned short* __restrict__ vtbf, unsigned short* __restrict__ outb)
{
    __shared__ unsigned short Pl[4][16][72];  // per-wave P staging
    __shared__ float Ol[4][16][33];           // partial O per wave (padded)
    __shared__ float Ml[4][16];
    __shared__ float Ll[4][16];
    const int tid = threadIdx.x, lane = tid & 63, w = tid >> 6;
    const int bh = blockIdx.y, b = bh >> 3, h = bh & 7;
    const int qbase = blockIdx.x * 16;
    const int lr = lane & 15, lg = lane >> 4;
    const float scl = 0.18257418583505536f; // 1/sqrt(30)
    const f32x4 czero = {0.f, 0.f, 0.f, 0.f};
    bf16x8 qf = *(const bf16x8*)&qbf[((size_t)bh * cSP + qbase + lr) * 32 + lg * 8];
    float m[4], l[4];
    f32x4 o0 = czero, o1 = czero;
#pragma unroll
    for (int r = 0; r < 4; ++r) { m[r] = -3.0e38f; l[r] = 0.f; }
    const int t0 = (qbase >= cPAST) ? 8 : 0;   // all-masked rows skip tiles < 8
    const int cnt = 17 - t0;
    const int ts = t0 + (w * cnt) / 4;
    const int te = t0 + ((w + 1) * cnt) / 4;
    const int qrow_b = qbase + lg * 4;
    for (int tt = ts; tt < te; ++tt) {
        const int kb = tt * 64;
        f32x4 c[4];
#pragma unroll
        for (int t = 0; t < 4; ++t) {
            bf16x8 kf = *(const bf16x8*)&kbf[((size_t)bh * cSP + kb + 16 * t + lr) * 32 + lg * 8];
            c[t] = __builtin_amdgcn_mfma_f32_16x16x32_bf16(qf, kf, czero, 0, 0, 0);
        }
#pragma unroll
        for (int t = 0; t < 4; ++t) {
            int key = kb + 16 * t + lr;
            bool koob = key >= cS;
            bool kpast = key < cPAST;
#pragma unroll
            for (int r = 0; r < 4; ++r) {
                float s = c[t][r] * scl;
                bool msk = koob || ((qrow_b + r >= cPAST) && kpast);
                c[t][r] = msk ? -3.0e38f : s;
            }
        }
        float mx[4];
#pragma unroll
        for (int r = 0; r < 4; ++r)
            mx[r] = fmaxf(fmaxf(c[0][r], c[1][r]), fmaxf(c[2][r], c[3][r]));
#pragma unroll
        for (int off = 1; off < 16; off <<= 1)
#pragma unroll
            for (int r = 0; r < 4; ++r)
                mx[r] = fmaxf(mx[r], __shfl_xor(mx[r], off));
        float corr[4], me[4], ps[4];
#pragma unroll
        for (int r = 0; r < 4; ++r) {
            float mn = fmaxf(m[r], mx[r]);
            corr[r] = __expf(m[r] - mn);
            m[r] = mn;
            me[r] = fmaxf(mn, -1.0e30f);  // floor: all-masked tile -> P = 0
            ps[r] = 0.f;
        }
#pragma unroll
        for (int t = 0; t < 4; ++t)
#pragma unroll
            for (int r = 0; r < 4; ++r) {
                float p = __expf(c[t][r] - me[r]);
                c[t][r] = p;
                ps[r] += p;
            }
#pragma unroll
        for (int off = 1; off < 16; off <<= 1)
#pragma unroll
            for (int r = 0; r < 4; ++r)
                ps[r] += __shfl_xor(ps[r], off);
#pragma unroll
        for (int r = 0; r < 4; ++r) {
            l[r] = l[r] * corr[r] + ps[r];
            o0[r] *= corr[r];
            o1[r] *= corr[r];
        }
#pragma unroll
        for (int t = 0; t < 4; ++t)
#pragma unroll
            for (int r = 0; r < 4; ++r)
                Pl[w][lg * 4 + r][16 * t + lr] = f2bf(c[t][r]);
#pragma unroll
        for (int c2 = 0; c2 < 2; ++c2) {
            bf16x8 pa  = *(const bf16x8*)&Pl[w][lr][c2 * 32 + lg * 8];
            bf16x8 bv0 = *(const bf16x8*)&vtbf[((size_t)bh * 32 + lr) * cSP + kb + c2 * 32 + lg * 8];
            bf16x8 bv1 = *(const bf16x8*)&vtbf[((size_t)bh * 32 + 16 + lr) * cSP + kb + c2 * 32 + lg * 8];
            o0 = __builtin_amdgcn_mfma_f32_16x16x32_bf16(pa, bv0, o0, 0, 0, 0);
            o1 = __builtin_amdgcn_mfma_f32_16x16x32_bf16(pa, bv1, o1, 0, 0, 0);
        }
    }
    // publish partials
#pragma unroll
    for (int r = 0; r < 4; ++r) {
        int row = lg * 4 + r;
        if (lr == 0) { Ml[w][row] = m[r]; Ll[w][row] = l[r]; }
        Ol[w][row][lr]      = o0[r];
        Ol[w][row][16 + lr] = o1[r];
    }
    __syncthreads();
    if (w == 0) {
        const int col = lane & 31, half = lane >> 5;
#pragma unroll
        for (int rr = 0; rr < 8; ++rr) {
            int row = half * 8 + rr;
            float M = fmaxf(fmaxf(Ml[0][row], Ml[1][row]), fmaxf(Ml[2][row], Ml[3][row]));
            float Lt = 0.f, Ot = 0.f;
#pragma unroll
            for (int ww = 0; ww < 4; ++ww) {
                float cc = __expf(Ml[ww][row] - M);
                Lt += Ll[ww][row] * cc;
                Ot += Ol[ww][row][col] * cc;
            }
            int q = qbase + row;
            if (q < cS && col < cHD)
                outb[((size_t)(b * cS + q)) * cKp + h * cHD + col] = f2bf(Ot / Lt);
        }
    }
}

// ------- fused GEMM (BM=16, BN=256) + residual + LayerNorm -------
// out = LN(A @ W^T + bias + Rs) ; FIN=1: write only rows>=PAST to outD, else f32+bf16.
template<int NK, int FIN>
__global__ __launch_bounds__(256) void gemm_ln(
    const unsigned short* __restrict__ A, const unsigned short* __restrict__ W,
    const float* __restrict__ bias, const float* __restrict__ Rs,
    const float* __restrict__ g, const float* __restrict__ be,
    float* __restrict__ outF, unsigned short* __restrict__ outB,
    float* __restrict__ outD, int KA)
{
    __shared__ unsigned short Al[16][40];
    __shared__ unsigned short Bl[256][40];
    __shared__ float Pr[4][4][4][2];   // [wave][kq][r][sum,sumsq]
    const int tid = threadIdx.x, lane = tid & 63, w = tid >> 6;
    const int lrow = lane & 15, kq = lane >> 4;
    const int rowBase = blockIdx.x * 16;
    const int arow = min(rowBase + (tid >> 4), cBS - 1);
    const int acp = tid & 15;
    const unsigned short* ap = A + (size_t)arow * KA + acp * 2;
    const unsigned short* wp = W + (size_t)tid * KA;
    unsigned int raA = *(const unsigned int*)ap;
    int4 rb0 = *(const int4*)(wp + 0);
    int4 rb1 = *(const int4*)(wp + 8);
    int4 rb2 = *(const int4*)(wp + 16);
    int4 rb3 = *(const int4*)(wp + 24);
    f32x4 acc[4] = {};
    for (int ks = 0; ks < NK; ++ks) {
        __syncthreads();
        *(unsigned int*)&Al[tid >> 4][acp * 2] = raA;
        *(int4*)&Bl[tid][0]  = rb0;
        *(int4*)&Bl[tid][8]  = rb1;
        *(int4*)&Bl[tid][16] = rb2;
        *(int4*)&Bl[tid][24] = rb3;
        __syncthreads();
        if (ks + 1 < NK) {
            int kk = (ks + 1) * 32;
            raA = *(const unsigned int*)(ap + kk);
            rb0 = *(const int4*)(wp + kk + 0);
            rb1 = *(const int4*)(wp + kk + 8);
            rb2 = *(const int4*)(wp + kk + 16);
            rb3 = *(const int4*)(wp + kk + 24);
        }
        bf16x8 af = *(const bf16x8*)&Al[lrow][kq * 8];
#pragma unroll
        for (int j = 0; j < 4; ++j) {
            bf16x8 bfr = *(const bf16x8*)&Bl[w * 64 + j * 16 + lrow][kq * 8];
            acc[j] = __builtin_amdgcn_mfma_f32_16x16x32_bf16(af, bfr, acc[j], 0, 0, 0);
        }
    }
    // epilogue: residual add + LN stats
    float val[4][4];
    float s1[4] = {0.f, 0.f, 0.f, 0.f}, s2[4] = {0.f, 0.f, 0.f, 0.f};
#pragma unroll
    for (int j = 0; j < 4; ++j) {
        int col = w * 64 + j * 16 + lrow;
        bool colok = col < cD;
        float bcol = colok ? bias[col] : 0.f;
#pragma unroll
        for (int r = 0; r < 4; ++r) {
            int row = rowBase + kq * 4 + r;
            float v = 0.f;
            if (colok && row < cBS) v = acc[j][r] + bcol + Rs[(size_t)row * cD + col];
            val[j][r] = v;
            s1[r] += v;
            s2[r] += v * v;
        }
    }
#pragma unroll
    for (int off = 1; off < 16; off <<= 1)
#pragma unroll
        for (int r = 0; r < 4; ++r) {
            s1[r] += __shfl_xor(s1[r], off);
            s2[r] += __shfl_xor(s2[r], off);
        }
    if (lrow == 0)
#pragma unroll
        for (int r = 0; r < 4; ++r) { Pr[w][kq][r][0] = s1[r]; Pr[w][kq][r][1] = s2[r]; }
    __syncthreads();
    float mean[4], rstd[4];
#pragma unroll
    for (int r = 0; r < 4; ++r) {
        float S = Pr[0][kq][r][0] + Pr[1][kq][r][0] + Pr[2][kq][r][0] + Pr[3][kq][r][0];
        float Q = Pr[0][kq][r][1] + Pr[1][kq][r][1] + Pr[2][kq][r][1] + Pr[3][kq][r][1];
        mean[r] = S * (1.0f / cD);
        float var = Q * (1.0f / cD) - mean[r] * mean[r];
        rstd[r] = rsqrtf(var + EPSF);
    }
#pragma unroll
    for (int j = 0; j < 4; ++j) {
        int col = w * 64 + j * 16 + lrow;
        if (col >= cD) continue;
        float gc = g[col], bc = be[col];
#pragma unroll
        for (int r = 0; r < 4; ++r) {
            int row = rowBase + kq * 4 + r;
            if (row >= cBS) continue;
            float y = (val[j][r] - mean[r]) * rstd[r] * gc + bc;
            if (FIN) {
                int bb = row / cS, ss = row - bb * cS;
                if (ss >= cPAST)
                    outD[((size_t)bb * (cS - cPAST) + (ss - cPAST)) * cD + col] = y;
            } else {
                outF[(size_t)row * cD + col] = y;
                outB[(size_t)row * cKp + col] = f2bf(y);
            }
        }
    }
}

extern "C" void kernel_launch(void* const* d_in, const int* in_sizes, int n_in,
                              void* d_out, int out_size, void* d_ws, size_t ws_size,
                              hipStream_t stream) {
    (void)in_sizes; (void)n_in; (void)out_size; (void)ws_size;
    const float* hand_t       = (const float*)d_in[0];
    const float* head_t       = (const float*)d_in[1];
    const float* hand_m1      = (const float*)d_in[2];
    const float* head_m1      = (const float*)d_in[3];
    const float* c_hand_t     = (const float*)d_in[4];
    const float* c_head_t     = (const float*)d_in[5];
    const float* c_hand_m1    = (const float*)d_in[6];
    const float* c_head_m1    = (const float*)d_in[7];
    const float* state_t      = (const float*)d_in[8];
    const float* state_m1     = (const float*)d_in[9];
    const float* hand_pose_m1 = (const float*)d_in[10];
    const float* head_pose_m1 = (const float*)d_in[11];
    const float* hand_pose_t  = (const float*)d_in[12];
    const float* head_pose_t  = (const float*)d_in[13];
    const float* Wq = (const float*)d_in[14];
    const float* Wk = (const float*)d_in[15];
    const float* Wv = (const float*)d_in[16];
    const float* Wo = (const float*)d_in[17];
    const float* W1 = (const float*)d_in[18];
    const float* W2 = (const float*)d_in[19];
    const float* bq = (const float*)d_in[20];
    const float* bk = (const float*)d_in[21];
    const float* bv = (const float*)d_in[22];
    const float* bo = (const float*)d_in[23];
    const float* b1 = (const float*)d_in[24];
    const float* b2 = (const float*)d_in[25];
    const float* g1 = (const float*)d_in[26];
    const float* be1 = (const float*)d_in[27];
    const float* g2 = (const float*)d_in[28];
    const float* be2 = (const float*)d_in[29];

    // ---- workspace layout ----
    char* p = (char*)d_ws;
    auto alloc_f = [&](size_t n) { float* r = (float*)p; p += n * sizeof(float); return r; };
    auto alloc_h = [&](size_t n) { unsigned short* r = (unsigned short*)p; p += n * sizeof(unsigned short); return r; };
    float* srcb  = alloc_f((size_t)cBS * cD);
    float* csb   = alloc_f((size_t)cBS * 4);
    float* s2b   = alloc_f((size_t)cBS * cD);
    unsigned short* src_bf  = alloc_h((size_t)cBS * cKp);
    unsigned short* s2_bf   = alloc_h((size_t)cBS * cKp);
    unsigned short* attn_bf = alloc_h((size_t)cBS * cKp);
    unsigned short* ff_bf   = alloc_h((size_t)cBS * cFF);
    unsigned short* qbf  = alloc_h(qkvN);
    unsigned short* kbf  = alloc_h(qkvN);
    unsigned short* vtbf = alloc_h(qkvN);
    unsigned short* wqkv = alloc_h((size_t)4 * cL * 65536);
    unsigned short* w1p  = alloc_h((size_t)cL * 1024 * 256);
    unsigned short* w2p  = alloc_h((size_t)cL * 256 * 1024);

    // ---- setup (single dispatch) ----
    setup_all<<<(R7 + 255) / 256, 256, 0, stream>>>(
        Wq, Wk, Wv, Wo, W1, W2,
        hand_t, head_t, hand_m1, head_m1, state_t, state_m1,
        hand_pose_m1, head_pose_m1, hand_pose_t, head_pose_t,
        c_hand_t, c_head_t, c_hand_m1, c_head_m1,
        wqkv, w1p, w2p, srcb, src_bf, csb,
        (unsigned int*)qbf, src_bf, s2_bf, attn_bf);

    const int mTiles = (cBS + 127) / 128;     // 33
    const int lnTiles = (cBS + 15) / 16;      // 258
    for (int l = 0; l < cL; ++l) {
        const unsigned short* wq_l = wqkv + (size_t)(0 * cL + l) * 65536;
        const unsigned short* wk_l = wqkv + (size_t)(1 * cL + l) * 65536;
        const unsigned short* wv_l = wqkv + (size_t)(2 * cL + l) * 65536;
        const unsigned short* wo_l = wqkv + (size_t)(3 * cL + l) * 65536;
        const unsigned short* w1_l = w1p + (size_t)l * 1024 * 256;
        const unsigned short* w2_l = w2p + (size_t)l * 256 * 1024;
        const float* bq_l = bq + (size_t)l * cD;
        const float* bk_l = bk + (size_t)l * cD;
        const float* bv_l = bv + (size_t)l * cD;
        const float* bo_l = bo + (size_t)l * cD;
        const float* b1_l = b1 + (size_t)l * cFF;
        const float* b2_l = b2 + (size_t)l * cD;
        const float* g1_l = g1 + (size_t)l * cD;
        const float* be1_l = be1 + (size_t)l * cD;
        const float* g2_l = g2 + (size_t)l * cD;
        const float* be2_l = be2 + (size_t)l * cD;

        gemm_qkv_rope<<<dim3(4, mTiles, 3), 256, 0, stream>>>(
            src_bf, wq_l, wk_l, wv_l, bq_l, bk_l, bv_l, csb, qbf, kbf, vtbf);
        attn_mfma<<<dim3((cS + 15) / 16, cB * cH), 256, 0, stream>>>(
            qbf, kbf, vtbf, attn_bf);
        gemm_ln<8, 0><<<lnTiles, 256, 0, stream>>>(
            attn_bf, wo_l, bo_l, srcb, g1_l, be1_l, s2b, s2_bf, nullptr, cKp);
        gemm_ff1<<<dim3(16, mTiles), 256, 0, stream>>>(
            s2_bf, w1_l, b1_l, ff_bf);
        if (l < cL - 1) {
            gemm_ln<32, 0><<<lnTiles, 256, 0, stream>>>(
                ff_bf, w2_l, b2_l, s2b, g2_l, be2_l, srcb, src_bf, nullptr, cFF);
        } else {
            gemm_ln<32, 1><<<lnTiles, 256, 0, stream>>>(
                ff_bf, w2_l, b2_l, s2b, g2_l, be2_l, nullptr, nullptr, (float*)d_out, cFF);
        }
    }
}

// Round 6
// 377.158 us; speedup vs baseline: 1.2596x; 1.2596x over previous
//
#include <hip/hip_runtime.h>
#include <cmath>

constexpr int cB = 4, cN = 256, cD = 240, cH = 8, cFF = 1024, cL = 4;
constexpr int cHD = 30, cS = 1030, cPAST = 515, cBS = cB * cS; // 4120
constexpr int cKp = 256;   // padded K for D-sized contractions
constexpr int cSP = 1088;  // padded sequence for attention buffers
constexpr float EPSF = 1e-5f;

typedef __bf16 bf16x8 __attribute__((ext_vector_type(8)));
typedef float f32x4 __attribute__((ext_vector_type(4)));

__device__ inline unsigned short f2bf(float f) {
    unsigned int u = __builtin_bit_cast(unsigned int, f);
    unsigned int r = (u + 0x7fffu + ((u >> 16) & 1u)) >> 16;
    return (unsigned short)r;
}

// =============== setup: weight convert + zero-init + embed + coords, one dispatch ==========
constexpr int R1 = 4 * cL * 65536;          // wqkv convert
constexpr int R2 = R1 + cL * 1024 * 256;    // w1p
constexpr int R3 = R2 + cL * 256 * 1024;    // w2p
constexpr int R4 = R3 + cBS * cD;           // embed
constexpr int R5 = R4 + cBS;                // coords
constexpr size_t qkvN = (size_t)cB * cH * cSP * 32;
constexpr int nSpan32 = (int)(3 * qkvN / 2);
constexpr int R6 = R5 + nSpan32;            // q/k/vT zero span (u32)
constexpr int R7 = R6 + cBS * 8;            // pad cols of 3 activation bufs (u32 each)

__global__ __launch_bounds__(256) void setup_all(
    const float* __restrict__ Wq, const float* __restrict__ Wk,
    const float* __restrict__ Wv, const float* __restrict__ Wo,
    const float* __restrict__ W1, const float* __restrict__ W2,
    const float* __restrict__ hand_t, const float* __restrict__ head_t,
    const float* __restrict__ hand_m1, const float* __restrict__ head_m1,
    const float* __restrict__ state_t, const float* __restrict__ state_m1,
    const float* __restrict__ hand_pose_m1, const float* __restrict__ head_pose_m1,
    const float* __restrict__ hand_pose_t, const float* __restrict__ head_pose_t,
    const float* __restrict__ ch_t, const float* __restrict__ cd_t,
    const float* __restrict__ ch_m1, const float* __restrict__ cd_m1,
    unsigned short* __restrict__ wqkv, unsigned short* __restrict__ w1p,
    unsigned short* __restrict__ w2p,
    float* __restrict__ src, unsigned short* __restrict__ sbf, float* __restrict__ cs,
    unsigned int* __restrict__ qkvspan,
    unsigned short* __restrict__ padA, unsigned short* __restrict__ padB,
    unsigned short* __restrict__ padC)
{
    int idx = blockIdx.x * 256 + threadIdx.x;
    if (idx < R1) {
        int which = idx >> 18;
        const float* W = (which == 0) ? Wq : (which == 1) ? Wk : (which == 2) ? Wv : Wo;
        int rem = idx & 262143;
        int m = rem >> 16;
        int rc = rem & 65535;
        int r = rc >> 8, c = rc & 255;
        float v = (r < 240 && c < 240) ? W[((size_t)m * 240 + r) * 240 + c] : 0.f;
        wqkv[idx] = f2bf(v);
    } else if (idx < R2) {
        int rem = idx - R1;
        int m = rem >> 18;
        int rc = rem & 262143;
        int r = rc >> 8, c = rc & 255;
        float v = (c < 240) ? W1[((size_t)m * 1024 + r) * 240 + c] : 0.f;
        w1p[rem] = f2bf(v);
    } else if (idx < R3) {
        int rem = idx - R2;
        int m = rem >> 18;
        int rc = rem & 262143;
        int r = rc >> 10, c = rc & 1023;
        float v = (r < 240) ? W2[((size_t)m * 240 + r) * 1024 + c] : 0.f;
        w2p[rem] = f2bf(v);
    } else if (idx < R4) {
        int rem = idx - R3;
        int d = rem % cD;
        int r = rem / cD;
        int b = r / cS, s = r % cS;
        const float* p; int off;
        if (s == 0)                  { p = state_m1;     off = b * cD + d; }
        else if (s == 1)             { p = hand_pose_m1; off = b * cD + d; }
        else if (s == 2)             { p = head_pose_m1; off = b * cD + d; }
        else if (s < 3 + cN)         { p = hand_m1;      off = (b * cN + (s - 3)) * cD + d; }
        else if (s < 3 + 2 * cN)     { p = head_m1;      off = (b * cN + (s - 3 - cN)) * cD + d; }
        else if (s == cPAST)         { p = state_t;      off = b * cD + d; }
        else if (s == cPAST + 1)     { p = hand_pose_t;  off = b * cD + d; }
        else if (s == cPAST + 2)     { p = head_pose_t;  off = b * cD + d; }
        else if (s < cPAST + 3 + cN) { p = hand_t;       off = (b * cN + (s - cPAST - 3)) * cD + d; }
        else                         { p = head_t;       off = (b * cN + (s - cPAST - 3 - cN)) * cD + d; }
        float v = p[off];
        src[rem] = v;
        sbf[(size_t)r * cKp + d] = f2bf(v);
    } else if (idx < R5) {
        int r = idx - R4;
        int b = r / cS, s = r % cS;
        float x = 0.f, y = 0.f, z = 0.f;
        const float* p = nullptr; int i = 0;
        if (s >= 3 && s < 3 + cN)                       { p = ch_m1; i = s - 3; }
        else if (s >= 3 + cN && s < 3 + 2 * cN)         { p = cd_m1; i = s - 3 - cN; }
        else if (s >= cPAST + 3 && s < cPAST + 3 + cN)  { p = ch_t;  i = s - cPAST - 3; }
        else if (s >= cPAST + 3 + cN)                   { p = cd_t;  i = s - cPAST - 3 - cN; }
        if (p) { x = p[(b * cN + i) * 3 + 0]; y = p[(b * cN + i) * 3 + 1]; z = p[(b * cN + i) * 3 + 2]; }
        cs[r * 3 + 0] = x; cs[r * 3 + 1] = y; cs[r * 3 + 2] = z;
    } else if (idx < R6) {
        qkvspan[idx - R5] = 0u;
    } else if (idx < R7) {
        int rem = idx - R6;
        int r = rem >> 3, j = rem & 7;
        ((unsigned int*)(padA + (size_t)r * 256 + 240))[j] = 0u;
        ((unsigned int*)(padB + (size_t)r * 256 + 240))[j] = 0u;
        ((unsigned int*)(padC + (size_t)r * 256 + 240))[j] = 0u;
    }
}

// ================= MFMA GEMM core, BM=128/BN=64 (rowBase defined by caller) ===============
#define GEMM_CORE128(A_PTR, W_PTR, M_, KA_, NK_)                                              \
    __shared__ unsigned short Al[128][40];                                                    \
    __shared__ unsigned short Bl[64][40];                                                     \
    const int tid = threadIdx.x;                                                              \
    const int lane = tid & 63;                                                                \
    const int w = tid >> 6;                                                                   \
    const int wm = w >> 1, wn = w & 1;                                                        \
    const int lrow = lane & 15, kq = lane >> 4;                                               \
    const int colBase = blockIdx.x * 64;                                                      \
    const int sRow = tid >> 2;                                                                \
    const int sS = tid & 3;                                                                   \
    const int ar0 = min(rowBase + sRow, M_ - 1);                                              \
    const int ar1 = min(rowBase + sRow + 64, M_ - 1);                                         \
    const int wr = colBase + sRow;                                                            \
    const unsigned short* a0p = A_PTR + (size_t)ar0 * KA_ + sS * 8;                           \
    const unsigned short* a1p = A_PTR + (size_t)ar1 * KA_ + sS * 8;                           \
    const unsigned short* wp  = W_PTR + (size_t)wr * KA_ + sS * 8;                            \
    f32x4 acc[4][2] = {};                                                                     \
    int4 ra0 = *(const int4*)a0p;                                                             \
    int4 ra1 = *(const int4*)a1p;                                                             \
    int4 rb  = *(const int4*)wp;                                                              \
    for (int ks = 0; ks < NK_; ++ks) {                                                        \
        __syncthreads();                                                                      \
        *(int4*)&Al[sRow][sS * 8]      = ra0;                                                 \
        *(int4*)&Al[sRow + 64][sS * 8] = ra1;                                                 \
        *(int4*)&Bl[sRow][sS * 8]      = rb;                                                  \
        __syncthreads();                                                                      \
        if (ks + 1 < NK_) {                                                                   \
            int kk = (ks + 1) * 32;                                                           \
            ra0 = *(const int4*)(a0p + kk);                                                   \
            ra1 = *(const int4*)(a1p + kk);                                                   \
            rb  = *(const int4*)(wp + kk);                                                    \
        }                                                                                     \
        bf16x8 af[4], bfr[2];                                                                 \
        _Pragma("unroll")                                                                     \
        for (int i = 0; i < 4; ++i)                                                           \
            af[i] = *(const bf16x8*)&Al[wm * 64 + i * 16 + lrow][kq * 8];                     \
        _Pragma("unroll")                                                                     \
        for (int j = 0; j < 2; ++j)                                                           \
            bfr[j] = *(const bf16x8*)&Bl[wn * 32 + j * 16 + lrow][kq * 8];                    \
        _Pragma("unroll")                                                                     \
        for (int i = 0; i < 4; ++i)                                                           \
            _Pragma("unroll")                                                                 \
            for (int j = 0; j < 2; ++j)                                                       \
                acc[i][j] = __builtin_amdgcn_mfma_f32_16x16x32_bf16(af[i], bfr[j], acc[i][j], 0, 0, 0); \
    }

// ================= MFMA GEMM core, BM=64/BN=64, wave tile 32x32 ===========================
#define GEMM_CORE64(A_PTR, W_PTR, M_, KA_, NK_)                                               \
    __shared__ unsigned short Al[64][40];                                                     \
    __shared__ unsigned short Bl[64][40];                                                     \
    const int tid = threadIdx.x;                                                              \
    const int lane = tid & 63;                                                                \
    const int w = tid >> 6;                                                                   \
    const int wm = w >> 1, wn = w & 1;                                                        \
    const int lrow = lane & 15, kq = lane >> 4;                                               \
    const int colBase = blockIdx.x * 64;                                                      \
    const int sRow = tid >> 2;                                                                \
    const int sS = tid & 3;                                                                   \
    const int ar0 = min(rowBase + sRow, M_ - 1);                                              \
    const int wr = colBase + sRow;                                                            \
    const unsigned short* a0p = A_PTR + (size_t)ar0 * KA_ + sS * 8;                           \
    const unsigned short* wp  = W_PTR + (size_t)wr * KA_ + sS * 8;                            \
    f32x4 acc[2][2] = {};                                                                     \
    int4 ra0 = *(const int4*)a0p;                                                             \
    int4 rb  = *(const int4*)wp;                                                              \
    for (int ks = 0; ks < NK_; ++ks) {                                                        \
        __syncthreads();                                                                      \
        *(int4*)&Al[sRow][sS * 8] = ra0;                                                      \
        *(int4*)&Bl[sRow][sS * 8] = rb;                                                       \
        __syncthreads();                                                                      \
        if (ks + 1 < NK_) {                                                                   \
            int kk = (ks + 1) * 32;                                                           \
            ra0 = *(const int4*)(a0p + kk);                                                   \
            rb  = *(const int4*)(wp + kk);                                                    \
        }                                                                                     \
        bf16x8 af[2], bfr[2];                                                                 \
        _Pragma("unroll")                                                                     \
        for (int i = 0; i < 2; ++i)                                                           \
            af[i] = *(const bf16x8*)&Al[wm * 32 + i * 16 + lrow][kq * 8];                     \
        _Pragma("unroll")                                                                     \
        for (int j = 0; j < 2; ++j)                                                           \
            bfr[j] = *(const bf16x8*)&Bl[wn * 32 + j * 16 + lrow][kq * 8];                    \
        _Pragma("unroll")                                                                     \
        for (int i = 0; i < 2; ++i)                                                           \
            _Pragma("unroll")                                                                 \
            for (int j = 0; j < 2; ++j)                                                       \
                acc[i][j] = __builtin_amdgcn_mfma_f32_16x16x32_bf16(af[i], bfr[j], acc[i][j], 0, 0, 0); \
    }

// ------- BM=64 GEMM + bias + residual -> f32 (O-proj, FF2). last: layer-3 tile map -------
template<int NK>
__global__ __launch_bounds__(256) void gemm_res64(
    const unsigned short* __restrict__ A, const unsigned short* __restrict__ W,
    const float* __restrict__ bias, const float* __restrict__ Rs,
    float* __restrict__ outF, int KA, int last)
{
    const int by = blockIdx.y;
    const int tileY = last ? (8 + 16 * (by / 9) + (by % 9)) : by;
    const int rowBase = tileY * 64;
    GEMM_CORE64(A, W, cBS, KA, NK)
#pragma unroll
    for (int i = 0; i < 2; ++i) {
#pragma unroll
        for (int j = 0; j < 2; ++j) {
            int col = colBase + wn * 32 + j * 16 + lrow;
            if (col >= cD) continue;
            float bcol = bias[col];
            f32x4 v = acc[i][j];
#pragma unroll
            for (int r = 0; r < 4; ++r) {
                int row = rowBase + wm * 32 + i * 16 + kq * 4 + r;
                if (row >= cBS) continue;
                outF[(size_t)row * cD + col] = v[r] + bcol + Rs[(size_t)row * cD + col];
            }
        }
    }
}

// ---------------- FF1 GEMM (BM=128): gelu(+bias) -> bf16 out (ld 1024) ----------------
__global__ __launch_bounds__(256) void gemm_ff1(
    const unsigned short* __restrict__ A, const unsigned short* __restrict__ W,
    const float* __restrict__ bias, unsigned short* __restrict__ outB, int last)
{
    const int by = blockIdx.y;
    const int tileY = last ? (4 + 8 * (by / 5) + (by % 5)) : by;
    const int rowBase = tileY * 128;
    GEMM_CORE128(A, W, cBS, cKp, 8)
#pragma unroll
    for (int i = 0; i < 4; ++i) {
#pragma unroll
        for (int j = 0; j < 2; ++j) {
            int col = colBase + wn * 32 + j * 16 + lrow;
            float bcol = bias[col];
            f32x4 v = acc[i][j];
#pragma unroll
            for (int r = 0; r < 4; ++r) {
                int row = rowBase + wm * 64 + i * 16 + kq * 4 + r;
                if (row >= cBS) continue;
                float t = v[r] + bcol;
                float gl = 0.5f * t * (1.0f + erff(t * 0.70710678118654752f));
                outB[(size_t)row * 1024 + col] = f2bf(gl);
            }
        }
    }
}

// ---------------- QKV GEMM with fused RoPE; writes bf16 q,k (BH,SP,32) and V^T (BH,32,SP) ----
__global__ __launch_bounds__(256) void gemm_qkv_rope(
    const unsigned short* __restrict__ A,
    const unsigned short* __restrict__ Wqp, const unsigned short* __restrict__ Wkp,
    const unsigned short* __restrict__ Wvp,
    const float* __restrict__ bq, const float* __restrict__ bk, const float* __restrict__ bv,
    const float* __restrict__ cs,
    unsigned short* __restrict__ qbf, unsigned short* __restrict__ kbf,
    unsigned short* __restrict__ vtbf)
{
    const int z = blockIdx.z;
    const unsigned short* Wsel = (z == 0) ? Wqp : (z == 1) ? Wkp : Wvp;
    const float* bias = (z == 0) ? bq : (z == 1) ? bk : bv;
    const int rowBase = blockIdx.y * 128;
    GEMM_CORE128(A, Wsel, cBS, cKp, 8)
    if (z == 2) {
#pragma unroll
        for (int i = 0; i < 4; ++i) {
#pragma unroll
            for (int j = 0; j < 2; ++j) {
                int col = colBase + wn * 32 + j * 16 + lrow;
                if (col >= cD) continue;
                float bcol = bias[col];
                int hh = col / cHD, hd = col % cHD;
                f32x4 vv = acc[i][j];
                int row0 = rowBase + wm * 64 + i * 16 + kq * 4;
                int b0 = row0 / cS, s0 = row0 - b0 * cS;
                if (row0 + 3 < cBS && s0 + 3 < cS) {
                    unsigned int lo = (unsigned)f2bf(vv[0] + bcol) | ((unsigned)f2bf(vv[1] + bcol) << 16);
                    unsigned int hi = (unsigned)f2bf(vv[2] + bcol) | ((unsigned)f2bf(vv[3] + bcol) << 16);
                    size_t base = ((size_t)(b0 * cH + hh) * 32 + hd) * cSP + s0;
                    *(unsigned int*)&vtbf[base]     = lo;
                    *(unsigned int*)&vtbf[base + 2] = hi;
                } else {
#pragma unroll
                    for (int r = 0; r < 4; ++r) {
                        int row = row0 + r;
                        if (row >= cBS) continue;
                        int bb = row / cS, ss = row - bb * cS;
                        vtbf[((size_t)(bb * cH + hh) * 32 + hd) * cSP + ss] = f2bf(vv[r] + bcol);
                    }
                }
            }
        }
    } else {
#pragma unroll
        for (int i = 0; i < 4; ++i) {
#pragma unroll
            for (int j = 0; j < 2; ++j) {
                int col = colBase + wn * 32 + j * 16 + lrow;
                bool colok = col < cD;
                int cc = colok ? col : 0;
                float bcol = colok ? bias[cc] : 0.f;
                int hh = cc / cHD, hd = cc % cHD;
                int a3 = hd / 10, jj = (hd % 10) >> 1;
                float invf = __expf(-1.8420680743952367f * (float)jj);
                f32x4 vv = acc[i][j];
#pragma unroll
                for (int r = 0; r < 4; ++r) {
                    int row = rowBase + wm * 64 + i * 16 + kq * 4 + r;
                    bool rowok = row < cBS;
                    int rowc = rowok ? row : 0;
                    float val = vv[r] + bcol;
                    float pval = __shfl_xor(val, 1);   // partner col (pairs are adjacent lanes)
                    int b = rowc / cS, s = rowc - b * cS;
                    size_t bh = (size_t)(b * cH + hh);
                    float ang = cs[rowc * 3 + a3] * invf;
                    float sn, co;
                    __sincosf(ang, &sn, &co);
                    float outv = (hd & 1) ? (pval * sn + val * co) : (val * co - pval * sn);
                    if (colok && rowok) {
                        unsigned short* dst = (z == 0) ? qbf : kbf;
                        dst[(bh * cSP + s) * 32 + hd] = f2bf(outv);
                    }
                }
            }
        }
    }
}

// ------- MFMA flash attention, kv-split x4: 16 q-rows/block, 4 waves = 4 kv quarters -------
__global__ __launch_bounds__(256) void attn_mfma(
    const unsigned short* __restrict__ qbf, const unsigned short* __restrict__ kbf,
    const unsigned short* __restrict__ vtbf, unsigned short* __restrict__ outb, int qt0)
{
    __shared__ unsigned short Pl[4][16][72];  // per-wave P staging
    __shared__ float Ol[4][16][33];           // partial O per wave (padded)
    __shared__ float Ml[4][16];
    __shared__ float Ll[4][16];
    const int tid = threadIdx.x, lane = tid & 63, w = tid >> 6;
    const int bh = blockIdx.y, b = bh >> 3, h = bh & 7;
    const int qbase = (qt0 + blockIdx.x) * 16;
    const int lr = lane & 15, lg = lane >> 4;
    const float scl = 0.18257418583505536f; // 1/sqrt(30)
    const f32x4 czero = {0.f, 0.f, 0.f, 0.f};
    bf16x8 qf = *(const bf16x8*)&qbf[((size_t)bh * cSP + qbase + lr) * 32 + lg * 8];
    float m[4], l[4];
    f32x4 o0 = czero, o1 = czero;
#pragma unroll
    for (int r = 0; r < 4; ++r) { m[r] = -3.0e38f; l[r] = 0.f; }
    const int t0 = (qbase >= cPAST) ? 8 : 0;   // all-masked rows skip tiles < 8
    const int cnt = 17 - t0;
    const int ts = t0 + (w * cnt) / 4;
    const int te = t0 + ((w + 1) * cnt) / 4;
    const int qrow_b = qbase + lg * 4;
    for (int tt = ts; tt < te; ++tt) {
        const int kb = tt * 64;
        f32x4 c[4];
#pragma unroll
        for (int t = 0; t < 4; ++t) {
            bf16x8 kf = *(const bf16x8*)&kbf[((size_t)bh * cSP + kb + 16 * t + lr) * 32 + lg * 8];
            c[t] = __builtin_amdgcn_mfma_f32_16x16x32_bf16(qf, kf, czero, 0, 0, 0);
        }
#pragma unroll
        for (int t = 0; t < 4; ++t) {
            int key = kb + 16 * t + lr;
            bool koob = key >= cS;
            bool kpast = key < cPAST;
#pragma unroll
            for (int r = 0; r < 4; ++r) {
                float s = c[t][r] * scl;
                bool msk = koob || ((qrow_b + r >= cPAST) && kpast);
                c[t][r] = msk ? -3.0e38f : s;
            }
        }
        float mx[4];
#pragma unroll
        for (int r = 0; r < 4; ++r)
            mx[r] = fmaxf(fmaxf(c[0][r], c[1][r]), fmaxf(c[2][r], c[3][r]));
#pragma unroll
        for (int off = 1; off < 16; off <<= 1)
#pragma unroll
            for (int r = 0; r < 4; ++r)
                mx[r] = fmaxf(mx[r], __shfl_xor(mx[r], off));
        float corr[4], me[4], ps[4];
#pragma unroll
        for (int r = 0; r < 4; ++r) {
            float mn = fmaxf(m[r], mx[r]);
            corr[r] = __expf(m[r] - mn);
            m[r] = mn;
            me[r] = fmaxf(mn, -1.0e30f);  // floor: all-masked tile -> P = 0
            ps[r] = 0.f;
        }
#pragma unroll
        for (int t = 0; t < 4; ++t)
#pragma unroll
            for (int r = 0; r < 4; ++r) {
                float p = __expf(c[t][r] - me[r]);
                c[t][r] = p;
                ps[r] += p;
            }
#pragma unroll
        for (int off = 1; off < 16; off <<= 1)
#pragma unroll
            for (int r = 0; r < 4; ++r)
                ps[r] += __shfl_xor(ps[r], off);
#pragma unroll
        for (int r = 0; r < 4; ++r) {
            l[r] = l[r] * corr[r] + ps[r];
            o0[r] *= corr[r];
            o1[r] *= corr[r];
        }
#pragma unroll
        for (int t = 0; t < 4; ++t)
#pragma unroll
            for (int r = 0; r < 4; ++r)
                Pl[w][lg * 4 + r][16 * t + lr] = f2bf(c[t][r]);
#pragma unroll
        for (int c2 = 0; c2 < 2; ++c2) {
            bf16x8 pa  = *(const bf16x8*)&Pl[w][lr][c2 * 32 + lg * 8];
            bf16x8 bv0 = *(const bf16x8*)&vtbf[((size_t)bh * 32 + lr) * cSP + kb + c2 * 32 + lg * 8];
            bf16x8 bv1 = *(const bf16x8*)&vtbf[((size_t)bh * 32 + 16 + lr) * cSP + kb + c2 * 32 + lg * 8];
            o0 = __builtin_amdgcn_mfma_f32_16x16x32_bf16(pa, bv0, o0, 0, 0, 0);
            o1 = __builtin_amdgcn_mfma_f32_16x16x32_bf16(pa, bv1, o1, 0, 0, 0);
        }
    }
    // publish partials
#pragma unroll
    for (int r = 0; r < 4; ++r) {
        int row = lg * 4 + r;
        if (lr == 0) { Ml[w][row] = m[r]; Ll[w][row] = l[r]; }
        Ol[w][row][lr]      = o0[r];
        Ol[w][row][16 + lr] = o1[r];
    }
    __syncthreads();
    if (w == 0) {
        const int col = lane & 31, half = lane >> 5;
#pragma unroll
        for (int rr = 0; rr < 8; ++rr) {
            int row = half * 8 + rr;
            float M = fmaxf(fmaxf(Ml[0][row], Ml[1][row]), fmaxf(Ml[2][row], Ml[3][row]));
            float Lt = 0.f, Ot = 0.f;
#pragma unroll
            for (int ww = 0; ww < 4; ++ww) {
                float cc = __expf(Ml[ww][row] - M);
                Lt += Ll[ww][row] * cc;
                Ot += Ol[ww][row][col] * cc;
            }
            int q = qbase + row;
            if (q < cS && col < cHD)
                outb[((size_t)(b * cS + q)) * cKp + h * cHD + col] = f2bf(Ot / Lt);
        }
    }
}

// ---------------- LayerNorm row helper (float4, one row per wave) ----------------
__device__ inline void ln_row_f4(const float* __restrict__ xr, const float* __restrict__ g,
                                 const float* __restrict__ be, float* __restrict__ yr,
                                 unsigned short* __restrict__ br, int lane)
{
    const bool ok = lane < 60;
    float4 v = make_float4(0.f, 0.f, 0.f, 0.f);
    if (ok) v = *(const float4*)(xr + 4 * lane);
    float sum = v.x + v.y + v.z + v.w;
#pragma unroll
    for (int off = 1; off < 64; off <<= 1) sum += __shfl_xor(sum, off);
    float mean = sum * (1.0f / cD);
    float vs = 0.f;
    if (ok) {
        float dx = v.x - mean, dy = v.y - mean, dz = v.z - mean, dw = v.w - mean;
        vs = dx * dx + dy * dy + dz * dz + dw * dw;
    }
#pragma unroll
    for (int off = 1; off < 64; off <<= 1) vs += __shfl_xor(vs, off);
    float rstd = rsqrtf(vs * (1.0f / cD) + EPSF);
    if (ok) {
        float4 g4 = *(const float4*)(g + 4 * lane);
        float4 b4 = *(const float4*)(be + 4 * lane);
        float4 y;
        y.x = (v.x - mean) * rstd * g4.x + b4.x;
        y.y = (v.y - mean) * rstd * g4.y + b4.y;
        y.z = (v.z - mean) * rstd * g4.z + b4.z;
        y.w = (v.w - mean) * rstd * g4.w + b4.w;
        *(float4*)(yr + 4 * lane) = y;
        if (br) {
            uint2 pk;
            pk.x = (unsigned)f2bf(y.x) | ((unsigned)f2bf(y.y) << 16);
            pk.y = (unsigned)f2bf(y.z) | ((unsigned)f2bf(y.w) << 16);
            *(uint2*)(br + 4 * lane) = pk;
        }
    }
}

// LN over all rows -> f32 (ld 240) + bf16 (ld 256)
__global__ __launch_bounds__(256) void ln_kernel(
    const float* __restrict__ x, const float* __restrict__ g,
    const float* __restrict__ be, float* __restrict__ y, unsigned short* __restrict__ ybf)
{
    int row = blockIdx.x * 4 + (threadIdx.x >> 6);
    int lane = threadIdx.x & 63;
    if (row >= cBS) return;
    ln_row_f4(x + (size_t)row * cD, g, be, y + (size_t)row * cD,
              ybf + (size_t)row * cKp, lane);
}

// LN over rows with s >= 512 only (layer-3 LN1)
__global__ __launch_bounds__(256) void ln_part(
    const float* __restrict__ x, const float* __restrict__ g,
    const float* __restrict__ be, float* __restrict__ y, unsigned short* __restrict__ ybf)
{
    constexpr int NR = cS - 512; // 518
    int idx = blockIdx.x * 4 + (threadIdx.x >> 6);
    int lane = threadIdx.x & 63;
    if (idx >= cB * NR) return;
    int row = (idx / NR) * cS + 512 + idx % NR;
    ln_row_f4(x + (size_t)row * cD, g, be, y + (size_t)row * cD,
              ybf + (size_t)row * cKp, lane);
}

// final LN2: rows s >= PAST straight into d_out
__global__ __launch_bounds__(256) void ln_final(
    const float* __restrict__ x, const float* __restrict__ g,
    const float* __restrict__ be, float* __restrict__ out)
{
    constexpr int NT = cS - cPAST; // 515
    int idx = blockIdx.x * 4 + (threadIdx.x >> 6);
    int lane = threadIdx.x & 63;
    if (idx >= cB * NT) return;
    int row = (idx / NT) * cS + cPAST + idx % NT;
    ln_row_f4(x + (size_t)row * cD, g, be, out + (size_t)idx * cD, nullptr, lane);
}

extern "C" void kernel_launch(void* const* d_in, const int* in_sizes, int n_in,
                              void* d_out, int out_size, void* d_ws, size_t ws_size,
                              hipStream_t stream) {
    (void)in_sizes; (void)n_in; (void)out_size; (void)ws_size;
    const float* hand_t       = (const float*)d_in[0];
    const float* head_t       = (const float*)d_in[1];
    const float* hand_m1      = (const float*)d_in[2];
    const float* head_m1      = (const float*)d_in[3];
    const float* c_hand_t     = (const float*)d_in[4];
    const float* c_head_t     = (const float*)d_in[5];
    const float* c_hand_m1    = (const float*)d_in[6];
    const float* c_head_m1    = (const float*)d_in[7];
    const float* state_t      = (const float*)d_in[8];
    const float* state_m1     = (const float*)d_in[9];
    const float* hand_pose_m1 = (const float*)d_in[10];
    const float* head_pose_m1 = (const float*)d_in[11];
    const float* hand_pose_t  = (const float*)d_in[12];
    const float* head_pose_t  = (const float*)d_in[13];
    const float* Wq = (const float*)d_in[14];
    const float* Wk = (const float*)d_in[15];
    const float* Wv = (const float*)d_in[16];
    const float* Wo = (const float*)d_in[17];
    const float* W1 = (const float*)d_in[18];
    const float* W2 = (const float*)d_in[19];
    const float* bq = (const float*)d_in[20];
    const float* bk = (const float*)d_in[21];
    const float* bv = (const float*)d_in[22];
    const float* bo = (const float*)d_in[23];
    const float* b1 = (const float*)d_in[24];
    const float* b2 = (const float*)d_in[25];
    const float* g1 = (const float*)d_in[26];
    const float* be1 = (const float*)d_in[27];
    const float* g2 = (const float*)d_in[28];
    const float* be2 = (const float*)d_in[29];

    // ---- workspace layout ----
    char* p = (char*)d_ws;
    auto alloc_f = [&](size_t n) { float* r = (float*)p; p += n * sizeof(float); return r; };
    auto alloc_h = [&](size_t n) { unsigned short* r = (unsigned short*)p; p += n * sizeof(unsigned short); return r; };
    float* srcb  = alloc_f((size_t)cBS * cD);
    float* csb   = alloc_f((size_t)cBS * 4);
    float* s2b   = alloc_f((size_t)cBS * cD);
    float* resid = alloc_f((size_t)cBS * cD);
    unsigned short* src_bf  = alloc_h((size_t)cBS * cKp);
    unsigned short* s2_bf   = alloc_h((size_t)cBS * cKp);
    unsigned short* attn_bf = alloc_h((size_t)cBS * cKp);
    unsigned short* ff_bf   = alloc_h((size_t)cBS * cFF);
    unsigned short* qbf  = alloc_h(qkvN);
    unsigned short* kbf  = alloc_h(qkvN);
    unsigned short* vtbf = alloc_h(qkvN);
    unsigned short* wqkv = alloc_h((size_t)4 * cL * 65536);
    unsigned short* w1p  = alloc_h((size_t)cL * 1024 * 256);
    unsigned short* w2p  = alloc_h((size_t)cL * 256 * 1024);

    // ---- setup (single dispatch) ----
    setup_all<<<(R7 + 255) / 256, 256, 0, stream>>>(
        Wq, Wk, Wv, Wo, W1, W2,
        hand_t, head_t, hand_m1, head_m1, state_t, state_m1,
        hand_pose_m1, head_pose_m1, hand_pose_t, head_pose_t,
        c_hand_t, c_head_t, c_hand_m1, c_head_m1,
        wqkv, w1p, w2p, srcb, src_bf, csb,
        (unsigned int*)qbf, src_bf, s2_bf, attn_bf);

    const int mTiles = (cBS + 127) / 128;     // 33
    const int mTiles64 = (cBS + 63) / 64;     // 65
    for (int l = 0; l < cL; ++l) {
        const int last = (l == cL - 1) ? 1 : 0;
        const unsigned short* wq_l = wqkv + (size_t)(0 * cL + l) * 65536;
        const unsigned short* wk_l = wqkv + (size_t)(1 * cL + l) * 65536;
        const unsigned short* wv_l = wqkv + (size_t)(2 * cL + l) * 65536;
        const unsigned short* wo_l = wqkv + (size_t)(3 * cL + l) * 65536;
        const unsigned short* w1_l = w1p + (size_t)l * 1024 * 256;
        const unsigned short* w2_l = w2p + (size_t)l * 256 * 1024;
        const float* bq_l = bq + (size_t)l * cD;
        const float* bk_l = bk + (size_t)l * cD;
        const float* bv_l = bv + (size_t)l * cD;
        const float* bo_l = bo + (size_t)l * cD;
        const float* b1_l = b1 + (size_t)l * cFF;
        const float* b2_l = b2 + (size_t)l * cD;
        const float* g1_l = g1 + (size_t)l * cD;
        const float* be1_l = be1 + (size_t)l * cD;
        const float* g2_l = g2 + (size_t)l * cD;
        const float* be2_l = be2 + (size_t)l * cD;

        gemm_qkv_rope<<<dim3(4, mTiles, 3), 256, 0, stream>>>(
            src_bf, wq_l, wk_l, wv_l, bq_l, bk_l, bv_l, csb, qbf, kbf, vtbf);

        if (!last) {
            attn_mfma<<<dim3(65, cB * cH), 256, 0, stream>>>(qbf, kbf, vtbf, attn_bf, 0);
            gemm_res64<8><<<dim3(4, mTiles64), 256, 0, stream>>>(
                attn_bf, wo_l, bo_l, srcb, resid, cKp, 0);
            ln_kernel<<<(cBS + 3) / 4, 256, 0, stream>>>(resid, g1_l, be1_l, s2b, s2_bf);
            gemm_ff1<<<dim3(16, mTiles), 256, 0, stream>>>(s2_bf, w1_l, b1_l, ff_bf, 0);
            gemm_res64<32><<<dim3(4, mTiles64), 256, 0, stream>>>(
                ff_bf, w2_l, b2_l, s2b, resid, cFF, 0);
            ln_kernel<<<(cBS + 3) / 4, 256, 0, stream>>>(resid, g2_l, be2_l, srcb, src_bf);
        } else {
            // layer 3: only rows s >= 512 matter for the output
            attn_mfma<<<dim3(33, cB * cH), 256, 0, stream>>>(qbf, kbf, vtbf, attn_bf, 32);
            gemm_res64<8><<<dim3(4, 36), 256, 0, stream>>>(
                attn_bf, wo_l, bo_l, srcb, resid, cKp, 1);
            ln_part<<<(cB * (cS - 512) + 3) / 4, 256, 0, stream>>>(
                resid, g1_l, be1_l, s2b, s2_bf);
            gemm_ff1<<<dim3(16, 20), 256, 0, stream>>>(s2_bf, w1_l, b1_l, ff_bf, 1);
            gemm_res64<32><<<dim3(4, 36), 256, 0, stream>>>(
                ff_bf, w2_l, b2_l, s2b, resid, cFF, 1);
            ln_final<<<(cB * (cS - cPAST) + 3) / 4, 256, 0, stream>>>(
                resid, g2_l, be2_l, (float*)d_out);
        }
    }
}